// Round 9
// baseline (105.368 us; speedup 1.0000x reference)
//
#include <hip/hip_runtime.h>

// Decoder: frames[m,c,k,l] = sum_n (mix[m,n,k]*mask[m,c,n,k]) * W[l,n]
// then overlap-add (hop=8) into out[m,c,t], T = (K-1)*8+16 = 128008.
// M=4 C=2 N=512 K=16000 L=16.
//
// TRAFFIC-MINIMAL variant: both c's per thread -> mix is loaded ONCE and
// used for both mask planes (issued vector-load bytes drop 524->393 MB,
// the mandatory minimum; r5-r8 showed the per-CU load path saturated at
// ~10.5 B/cyc/CU, so issued bytes ~ time). Scalar k per lane (BK=64),
// lean 2-n chunks, uniform SGPR bases + 32-bit voffsets, acc[2][16].
// __launch_bounds__(256,8) targets <=64 VGPR / 32 waves/CU.
// W via scalar path (uniform address -> s_load dwordx2, constant cache).
// LDS: 15.4 KB reduce buffer, reused across two c-phases (8 blocks/CU ->
// 123 KB < 160). Wave 0 overlap-adds in-register via shfl_up; boundary
// head/tail partials -> d_ws; boundary_kernel combines: every out element
// written exactly once with '=' (no memset, no atomics, replay-safe).

#define M_   4
#define C_   2
#define N_   512
#define K_   16000
#define L_   16
#define HOP  8
#define T_   ((K_ - 1) * HOP + L_)   // 128008
#define BK   64                      // frames per block (1 per lane)
#define NSEG 4                       // waves per block
#define NPW  (N_ / NSEG)             // 128 n's per wave
#define NCH  (NPW / 2)               // 64 chunks of 2 n's
#define NB   (K_ / BK)               // 250 k-blocks per m
#define GRID (M_ * NB)               // 1000
#define RSTRIDE 20                   // reduce-buffer lane stride (floats)
#define WS_TAIL_OFF (M_ * C_ * NB * 8)

__global__ __launch_bounds__(256, 8)
void decoder_kernel(const float* __restrict__ mix,   // [M][N][K]
                    const float* __restrict__ mask,  // [M][C][N][K]
                    const float* __restrict__ Wg,    // [L][N]
                    float* __restrict__ out,         // [M][C][T]
                    float* __restrict__ ws) {
    __shared__ float lds[3 * 64 * RSTRIDE];          // 15.4 KB

    const int tid  = threadIdx.x;
    const int lane = tid & 63;
    const int w    = tid >> 6;
    const int m    = blockIdx.x / NB;
    const int bb   = blockIdx.x % NB;
    const int k0   = bb * BK;

    float acc0[16], acc1[16];        // [l] for c=0 / c=1
    #pragma unroll
    for (int i = 0; i < 16; ++i) { acc0[i] = 0.f; acc1[i] = 0.f; }

    const int n0w  = w * NPW;
    const int n0wU = __builtin_amdgcn_readfirstlane(n0w);  // uniform -> s_load
    const int kk   = k0 + lane;

    // uniform SGPR bases; per-lane state is a single 32-bit element offset
    const float* mixB = mix  + (size_t)m * N_ * K_ + (size_t)n0w * K_;
    const float* m0B  = mask + ((size_t)(m * C_) * N_ + n0w) * K_;
    const float* m1B  = m0B + (size_t)N_ * K_;             // c=1 plane
    int off = kk;                                          // += 2*K_ per chunk

    #pragma unroll 2
    for (int ch = 0; ch < NCH; ++ch) {
        const int o0 = off, o1 = off + K_;
        const float mv0 = mixB[o0], mv1 = mixB[o1];
        const float a00 = m0B[o0],  a01 = m0B[o1];
        const float a10 = m1B[o0],  a11 = m1B[o1];
        const float s00 = mv0 * a00, s01 = mv1 * a01;      // c0: n0, n1
        const float s10 = mv0 * a10, s11 = mv1 * a11;      // c1: n0, n1

        const int nbase = n0wU + ch * 2;                   // scalar
        #pragma unroll
        for (int l = 0; l < L_; ++l) {
            const float2 w2 = *(const float2*)&Wg[l * N_ + nbase];  // s_load
            acc0[l] = fmaf(s00, w2.x, acc0[l]);
            acc0[l] = fmaf(s01, w2.y, acc0[l]);
            acc1[l] = fmaf(s10, w2.x, acc1[l]);
            acc1[l] = fmaf(s11, w2.y, acc1[l]);
        }
        off += 2 * K_;
    }

    // ---- cross-wave reduction through LDS, one phase per c ----
    auto reduce_c = [&](float (&acc)[16]) {
        __syncthreads();             // also separates prev phase's reads
        if (w > 0) {
            float* rb = &lds[(w - 1) * (64 * RSTRIDE) + lane * RSTRIDE];
            #pragma unroll
            for (int i = 0; i < 4; ++i)
                *(float4*)&rb[i * 4] = make_float4(acc[i*4], acc[i*4+1],
                                                   acc[i*4+2], acc[i*4+3]);
        }
        __syncthreads();
        if (w == 0) {
            #pragma unroll
            for (int r = 0; r < 3; ++r) {
                const float* rb = &lds[r * (64 * RSTRIDE) + lane * RSTRIDE];
                #pragma unroll
                for (int i = 0; i < 4; ++i) {
                    const float4 v = *(const float4*)&rb[i * 4];
                    acc[i*4]   += v.x;  acc[i*4+1] += v.y;
                    acc[i*4+2] += v.z;  acc[i*4+3] += v.w;
                }
            }
        }
    };
    reduce_c(acc0);
    reduce_c(acc1);

    // ---- overlap-add: t = k*8+j = frames[k][j] + frames[k-1][8+j] ----
    if (w == 0) {
#define EPILOGUE(ACC, CIDX)                                                   \
        {                                                                     \
            float* ob = out + (size_t)(m * C_ + (CIDX)) * T_                  \
                            + (size_t)kk * HOP;                               \
            float cmb[8];                                                     \
            _Pragma("unroll")                                                 \
            for (int j = 0; j < 8; ++j) {                                     \
                const float pv = __shfl_up(ACC[8 + j], 1);                    \
                cmb[j] = ACC[j] + pv;                                         \
            }                                                                 \
            if (lane == 0) {                                                  \
                float* hb = ws + (size_t)((m * C_ + (CIDX)) * NB + bb) * 8;   \
                *(float4*)&hb[0] = make_float4(ACC[0], ACC[1], ACC[2], ACC[3]);\
                *(float4*)&hb[4] = make_float4(ACC[4], ACC[5], ACC[6], ACC[7]);\
            } else {                                                          \
                *(float4*)&ob[0] = make_float4(cmb[0], cmb[1], cmb[2], cmb[3]);\
                *(float4*)&ob[4] = make_float4(cmb[4], cmb[5], cmb[6], cmb[7]);\
            }                                                                 \
            if (lane == 63) {                                                 \
                float* tb = ws + WS_TAIL_OFF                                  \
                             + (size_t)((m * C_ + (CIDX)) * NB + bb) * 8;     \
                *(float4*)&tb[0] = make_float4(ACC[8],  ACC[9],               \
                                               ACC[10], ACC[11]);             \
                *(float4*)&tb[4] = make_float4(ACC[12], ACC[13],              \
                                               ACC[14], ACC[15]);             \
            }                                                                 \
        }
        EPILOGUE(acc0, 0)
        EPILOGUE(acc1, 1)
#undef EPILOGUE
    }
}

// out[bb*512 + j] = head[bb] + tail[bb-1]; global tail = tail[NB-1].
__global__ __launch_bounds__(256)
void boundary_kernel(const float* __restrict__ ws, float* __restrict__ out) {
    const int id = blockIdx.x * 256 + threadIdx.x;
    const int total = M_ * C_ * NB * 8;
    if (id >= total) return;
    const int j  = id & 7;
    const int bb = (id >> 3) % NB;
    const int mc = (id >> 3) / NB;
    float v = ws[(size_t)(mc * NB + bb) * 8 + j];
    if (bb > 0) v += ws[WS_TAIL_OFF + (size_t)(mc * NB + bb - 1) * 8 + j];
    out[(size_t)mc * T_ + (size_t)bb * (BK * HOP) + j] = v;
    if (bb == NB - 1) {
        out[(size_t)mc * T_ + (size_t)K_ * HOP + j] =
            ws[WS_TAIL_OFF + (size_t)(mc * NB + bb) * 8 + j];
    }
}

extern "C" void kernel_launch(void* const* d_in, const int* in_sizes, int n_in,
                              void* d_out, int out_size, void* d_ws, size_t ws_size,
                              hipStream_t stream) {
    const float* mix  = (const float*)d_in[0];
    const float* mask = (const float*)d_in[1];
    const float* Wg   = (const float*)d_in[2];
    float* out = (float*)d_out;
    float* ws  = (float*)d_ws;

    decoder_kernel<<<dim3(GRID), dim3(256), 0, stream>>>(mix, mask, Wg, out, ws);
    boundary_kernel<<<dim3((M_ * C_ * NB * 8 + 255) / 256), dim3(256), 0, stream>>>(ws, out);
}

// Round 10
// 88.055 us; speedup vs baseline: 1.1966x; 1.1966x over previous
//
#include <hip/hip_runtime.h>

// Decoder: frames[m,c,k,l] = sum_n (mix[m,n,k]*mask[m,c,n,k]) * W[l,n]
// then overlap-add (hop=8) into out[m,c,t], T = (K-1)*8+16 = 128008.
// M=4 C=2 N=512 K=16000 L=16.
//
// TRAFFIC-MINIMAL, resource-corrected (r9 spilled under the 64-VGPR cap):
// both c's per thread -> mix loaded ONCE, shared across both mask planes
// (issued vector-load bytes = 393 MB, the mandatory minimum; the per-CU
// load path saturates at ~6.5 TB/s logical, so issued bytes ~ time).
// __launch_bounds__(256,4): <=128 VGPR, no spill, 16 waves/CU.
// Scalar k per lane (BK=64), 4-n chunks (12 dword loads / 136 VALU),
// grid 1000. W via scalar path (uniform address -> s_load float4 through
// constant cache; FMA consumes SGPR operand). LDS: 15.4 KB reduce buffer
// reused across two c-phases. Wave 0 overlap-adds in-register via shfl_up;
// boundary head/tail partials -> d_ws; boundary_kernel combines them:
// every out element written exactly once with '=' (no memset, no atomics).

#define M_   4
#define C_   2
#define N_   512
#define K_   16000
#define L_   16
#define HOP  8
#define T_   ((K_ - 1) * HOP + L_)   // 128008
#define BK   64                      // frames per block (1 per lane)
#define NSEG 4                       // waves per block
#define NPW  (N_ / NSEG)             // 128 n's per wave
#define NCH  (NPW / 4)               // 32 chunks of 4 n's
#define NB   (K_ / BK)               // 250 k-blocks per m
#define GRID (M_ * NB)               // 1000
#define RSTRIDE 20                   // reduce-buffer lane stride (floats)
#define WS_TAIL_OFF (M_ * C_ * NB * 8)

__global__ __launch_bounds__(256, 4)
void decoder_kernel(const float* __restrict__ mix,   // [M][N][K]
                    const float* __restrict__ mask,  // [M][C][N][K]
                    const float* __restrict__ Wg,    // [L][N]
                    float* __restrict__ out,         // [M][C][T]
                    float* __restrict__ ws) {
    __shared__ float lds[3 * 64 * RSTRIDE];          // 15.4 KB

    const int tid  = threadIdx.x;
    const int lane = tid & 63;
    const int w    = tid >> 6;
    const int m    = blockIdx.x / NB;
    const int bb   = blockIdx.x % NB;
    const int k0   = bb * BK;

    float acc0[16], acc1[16];        // [l] for c=0 / c=1
    #pragma unroll
    for (int i = 0; i < 16; ++i) { acc0[i] = 0.f; acc1[i] = 0.f; }

    const int n0w  = w * NPW;
    const int n0wU = __builtin_amdgcn_readfirstlane(n0w);  // uniform -> s_load
    const int kk   = k0 + lane;

    const float* pm = mix  + (size_t)m * N_ * K_ + (size_t)n0w * K_ + kk;
    const float* p0 = mask + ((size_t)(m * C_) * N_ + n0w) * K_ + kk;
    const float* p1 = p0 + (size_t)N_ * K_;                // c=1 plane

    #pragma unroll 2
    for (int ch = 0; ch < NCH; ++ch) {
        float mv[4], a0[4], a1[4];
        #pragma unroll
        for (int j = 0; j < 4; ++j) {
            mv[j] = pm[(size_t)j * K_];
            a0[j] = p0[(size_t)j * K_];
            a1[j] = p1[(size_t)j * K_];
        }
        float s0[4], s1[4];
        #pragma unroll
        for (int j = 0; j < 4; ++j) { s0[j] = mv[j] * a0[j]; s1[j] = mv[j] * a1[j]; }

        const int nbase = n0wU + ch * 4;                   // scalar
        #pragma unroll
        for (int l = 0; l < L_; ++l) {
            const float4 w4 = *(const float4*)&Wg[l * N_ + nbase];  // s_load
            acc0[l] = fmaf(s0[0], w4.x, acc0[l]);
            acc0[l] = fmaf(s0[1], w4.y, acc0[l]);
            acc0[l] = fmaf(s0[2], w4.z, acc0[l]);
            acc0[l] = fmaf(s0[3], w4.w, acc0[l]);
            acc1[l] = fmaf(s1[0], w4.x, acc1[l]);
            acc1[l] = fmaf(s1[1], w4.y, acc1[l]);
            acc1[l] = fmaf(s1[2], w4.z, acc1[l]);
            acc1[l] = fmaf(s1[3], w4.w, acc1[l]);
        }
        pm += (size_t)4 * K_;
        p0 += (size_t)4 * K_;
        p1 += (size_t)4 * K_;
    }

    // ---- cross-wave reduction through LDS, one phase per c ----
    auto reduce_c = [&](float (&acc)[16]) {
        __syncthreads();             // also separates prev phase's reads
        if (w > 0) {
            float* rb = &lds[(w - 1) * (64 * RSTRIDE) + lane * RSTRIDE];
            #pragma unroll
            for (int i = 0; i < 4; ++i)
                *(float4*)&rb[i * 4] = make_float4(acc[i*4], acc[i*4+1],
                                                   acc[i*4+2], acc[i*4+3]);
        }
        __syncthreads();
        if (w == 0) {
            #pragma unroll
            for (int r = 0; r < 3; ++r) {
                const float* rb = &lds[r * (64 * RSTRIDE) + lane * RSTRIDE];
                #pragma unroll
                for (int i = 0; i < 4; ++i) {
                    const float4 v = *(const float4*)&rb[i * 4];
                    acc[i*4]   += v.x;  acc[i*4+1] += v.y;
                    acc[i*4+2] += v.z;  acc[i*4+3] += v.w;
                }
            }
        }
    };
    reduce_c(acc0);
    reduce_c(acc1);

    // ---- overlap-add: t = k*8+j = frames[k][j] + frames[k-1][8+j] ----
    if (w == 0) {
#define EPILOGUE(ACC, CIDX)                                                   \
        {                                                                     \
            float* ob = out + (size_t)(m * C_ + (CIDX)) * T_                  \
                            + (size_t)kk * HOP;                               \
            float cmb[8];                                                     \
            _Pragma("unroll")                                                 \
            for (int j = 0; j < 8; ++j) {                                     \
                const float pv = __shfl_up(ACC[8 + j], 1);                    \
                cmb[j] = ACC[j] + pv;                                         \
            }                                                                 \
            if (lane == 0) {                                                  \
                float* hb = ws + (size_t)((m * C_ + (CIDX)) * NB + bb) * 8;   \
                *(float4*)&hb[0] = make_float4(ACC[0], ACC[1], ACC[2], ACC[3]);\
                *(float4*)&hb[4] = make_float4(ACC[4], ACC[5], ACC[6], ACC[7]);\
            } else {                                                          \
                *(float4*)&ob[0] = make_float4(cmb[0], cmb[1], cmb[2], cmb[3]);\
                *(float4*)&ob[4] = make_float4(cmb[4], cmb[5], cmb[6], cmb[7]);\
            }                                                                 \
            if (lane == 63) {                                                 \
                float* tb = ws + WS_TAIL_OFF                                  \
                             + (size_t)((m * C_ + (CIDX)) * NB + bb) * 8;     \
                *(float4*)&tb[0] = make_float4(ACC[8],  ACC[9],               \
                                               ACC[10], ACC[11]);             \
                *(float4*)&tb[4] = make_float4(ACC[12], ACC[13],              \
                                               ACC[14], ACC[15]);             \
            }                                                                 \
        }
        EPILOGUE(acc0, 0)
        EPILOGUE(acc1, 1)
#undef EPILOGUE
    }
}

// out[bb*512 + j] = head[bb] + tail[bb-1]; global tail = tail[NB-1].
__global__ __launch_bounds__(256)
void boundary_kernel(const float* __restrict__ ws, float* __restrict__ out) {
    const int id = blockIdx.x * 256 + threadIdx.x;
    const int total = M_ * C_ * NB * 8;
    if (id >= total) return;
    const int j  = id & 7;
    const int bb = (id >> 3) % NB;
    const int mc = (id >> 3) / NB;
    float v = ws[(size_t)(mc * NB + bb) * 8 + j];
    if (bb > 0) v += ws[WS_TAIL_OFF + (size_t)(mc * NB + bb - 1) * 8 + j];
    out[(size_t)mc * T_ + (size_t)bb * (BK * HOP) + j] = v;
    if (bb == NB - 1) {
        out[(size_t)mc * T_ + (size_t)K_ * HOP + j] =
            ws[WS_TAIL_OFF + (size_t)(mc * NB + bb) * 8 + j];
    }
}

extern "C" void kernel_launch(void* const* d_in, const int* in_sizes, int n_in,
                              void* d_out, int out_size, void* d_ws, size_t ws_size,
                              hipStream_t stream) {
    const float* mix  = (const float*)d_in[0];
    const float* mask = (const float*)d_in[1];
    const float* Wg   = (const float*)d_in[2];
    float* out = (float*)d_out;
    float* ws  = (float*)d_ws;

    decoder_kernel<<<dim3(GRID), dim3(256), 0, stream>>>(mix, mask, Wg, out, ws);
    boundary_kernel<<<dim3((M_ * C_ * NB * 8 + 255) / 256), dim3(256), 0, stream>>>(ws, out);
}